// Round 2
// baseline (90.588 us; speedup 1.0000x reference)
//
#include <hip/hip_runtime.h>
#include <hip/hip_bf16.h>

// out[n,v] = x[n,v] + sum_{c<v} x[n,c] * sum_k B_k(x[n,c]) * params[k, v(v-1)/2+c]
// Fused as GEMM: G[n][c*16+k] = x[n,c]*B_k(x[n,c]);  W2T[v][c*16+k] = params or 0
// out = x + G @ W2,  via mfma_f32_16x16x32_f16.

#define NSAMP 131072
#define PPAIR 496

typedef _Float16 f16x8 __attribute__((ext_vector_type(8)));
typedef float f32x4 __attribute__((ext_vector_type(4)));
typedef unsigned int uint32;
typedef unsigned short ushort16;

// ---- prep: build W2T [32][512] f16 from params [16][496] f32 ----
__global__ __launch_bounds__(256) void prep_w2t(const float* __restrict__ params,
                                                ushort16* __restrict__ w2t) {
    int idx = blockIdx.x * 256 + threadIdx.x;   // 0 .. 32*512-1
    int v = idx >> 9;
    int ck = idx & 511;
    int c = ck >> 4, k = ck & 15;
    float w = 0.0f;
    if (c < v) w = params[k * PPAIR + (v * (v - 1)) / 2 + c];
    _Float16 h = (_Float16)w;
    w2t[idx] = __builtin_bit_cast(ushort16, h);
}

__device__ __forceinline__ float invden(int d) {
    // d in {1,2,3}; den = d * h, h = 12/13  ->  1/den
    return d == 1 ? (13.0f / 12.0f) : (d == 2 ? (13.0f / 24.0f) : (13.0f / 36.0f));
}

__global__ __launch_bounds__(256, 2) void decor_main(const float* __restrict__ xin,
                                                     const ushort16* __restrict__ w2t,
                                                     float* __restrict__ out) {
    // per-wave G tile: 16 samples x 512 (c*16+k) f16, row padded to 520 (1040B, 16B-aligned)
    __shared__ __align__(16) ushort16 G[4][16][520];

    const int tid = threadIdx.x;
    const int w = tid >> 6;
    const int l = tid & 63;
    const int s = l & 15;   // sample-in-tile / MFMA row-col lane id
    const int q = l >> 4;   // quarter-wave id

    // ---- B fragments held in registers: bfrag[t][nt][j] = W2T[nt*16+s][t*32+q*8+j]
    f16x8 bfrag[16][2];
#pragma unroll
    for (int t = 0; t < 16; ++t) {
#pragma unroll
        for (int nt = 0; nt < 2; ++nt) {
            int n = nt * 16 + s;
            bfrag[t][nt] = *(const f16x8*)(w2t + n * 512 + t * 32 + q * 8);
        }
    }

    const float lo = -6.0f;
    const float hk = 12.0f / 13.0f;     // knot spacing
    const float inv_h = 13.0f / 12.0f;
    const float xmax = 6.0f - 1.2e-5f;  // hi - 1e-6*(hi-lo)

    uint32* const Gdw = (uint32*)&G[w][0][0];   // dword view of this wave's tile (row stride 260 dw)

    for (int tile = 0; tile < 4; ++tile) {
        const int S0 = blockIdx.x * 256 + w * 64 + tile * 16;

        // ---- zero the used 512 cols (256 dwords) of all 16 rows:
        //      16 rows x 64 uint4-chunks = 1024 chunks; 64 lanes -> 16 iterations
#pragma unroll
        for (int it = 0; it < 16; ++it) {
            int chunk = it * 64 + l;            // 0..1023
            int row = chunk >> 6, ci = chunk & 63;
            *(uint4*)(Gdw + row * 260 + ci * 4) = make_uint4(0u, 0u, 0u, 0u);
        }

        // ---- basis + sparse G writes: lane handles (s, c = q + 4a), a = 0..7
#pragma unroll
        for (int a = 0; a < 8; ++a) {
            int c = q + 4 * a;
            float x = xin[(S0 + s) * 32 + c];
            float xc = fminf(fmaxf(x, lo), xmax);
            float u = (xc - lo) * inv_h;
            int m = (int)u;                 // floor (u >= 0)
            m = m < 12 ? m : 12;            // span index 0..12, k0 = m

            // clamped knot integer offsets (t-index - 3), values kn(q) = lo + hk*clamp(q,0,13)
            int q0 = m - 2 > 0 ? m - 2 : 0;
            int q1 = m - 1 > 0 ? m - 1 : 0;
            int q4 = m + 2 < 13 ? m + 2 : 13;
            int q5 = m + 3 < 13 ? m + 3 : 13;
            float km  = fmaf((float)m,       hk, lo);
            float km1 = fmaf((float)(m + 1), hk, lo);
            float kq0 = fmaf((float)q0, hk, lo);
            float kq1 = fmaf((float)q1, hk, lo);
            float kq4 = fmaf((float)q4, hk, lo);
            float kq5 = fmaf((float)q5, hk, lo);
            float left1 = xc - km,  right1 = km1 - xc;
            float left2 = xc - kq1, right2 = kq4 - xc;
            float left3 = xc - kq0, right3 = kq5 - xc;

            // NURBS BasisFuns, unrolled, divides replaced by exact-gap reciprocal selects
            float T, sv;
            T = 13.0f / 12.0f;              // 1 / (right1+left1) = 1/h
            float N0 = right1 * T;
            float N1 = left1 * T;
            // j = 2
            T = N0 * invden((m + 1) - q1);
            N0 = right1 * T;
            sv = left2 * T;
            T = N1 * invden(q4 - m);
            N1 = fmaf(right2, T, sv);
            sv = left1 * T;
            float N2 = sv;
            // j = 3
            T = N0 * invden((m + 1) - q0);
            N0 = right1 * T;
            sv = left3 * T;
            T = N1 * invden(q4 - q1);
            N1 = fmaf(right2, T, sv);
            sv = left2 * T;
            T = N2 * invden(q5 - m);
            N2 = fmaf(right3, T, sv);
            sv = left1 * T;
            float N3 = sv;

            // G entries: original (unclipped) x times basis; slots m..m+3 of channel block
            float g0 = x * N0, g1 = x * N1, g2 = x * N2, g3 = x * N3;
            int e = m & 1;
            float a0 = e ? 0.0f : g0, b0 = e ? g0 : g1;
            float a1 = e ? g1 : g2,   b1 = e ? g2 : g3;
            uint32 d0 = __builtin_bit_cast(uint32, __builtin_amdgcn_cvt_pkrtz(a0, b0));
            uint32 d1 = __builtin_bit_cast(uint32, __builtin_amdgcn_cvt_pkrtz(a1, b1));
            uint32* rowp = (uint32*)&G[w][s][0];
            int dwb = c * 8 + (m >> 1);     // dword index within row
            rowp[dwb] = d0;
            rowp[dwb + 1] = d1;
            if (e) {
                uint32 d2 = __builtin_bit_cast(uint32, __builtin_amdgcn_cvt_pkrtz(g3, 0.0f));
                rowp[dwb + 2] = d2;
            }
        }
        __syncthreads();

        // ---- MFMA: acc[nt] over K=512 in 16 steps
        f32x4 acc0 = {0.0f, 0.0f, 0.0f, 0.0f};
        f32x4 acc1 = {0.0f, 0.0f, 0.0f, 0.0f};
#pragma unroll
        for (int t = 0; t < 16; ++t) {
            f16x8 af = *(const f16x8*)&G[w][s][t * 32 + q * 8];
            acc0 = __builtin_amdgcn_mfma_f32_16x16x32_f16(af, bfrag[t][0], acc0, 0, 0, 0);
            acc1 = __builtin_amdgcn_mfma_f32_16x16x32_f16(af, bfrag[t][1], acc1, 0, 0, 0);
        }

        // ---- epilogue: D[row=(q*4+r)][col=s(+16)] ; out = x + D
#pragma unroll
        for (int r = 0; r < 4; ++r) {
            int sample = S0 + q * 4 + r;
            int base = sample * 32;
            out[base + s]      = xin[base + s]      + acc0[r];
            out[base + 16 + s] = xin[base + 16 + s] + acc1[r];
        }
        __syncthreads();
    }
}

extern "C" void kernel_launch(void* const* d_in, const int* in_sizes, int n_in,
                              void* d_out, int out_size, void* d_ws, size_t ws_size,
                              hipStream_t stream) {
    const float* xin = (const float*)d_in[0];
    const float* params = (const float*)d_in[1];
    float* out = (float*)d_out;
    ushort16* w2t = (ushort16*)d_ws;   // 32*512 f16 = 32 KB scratch

    prep_w2t<<<64, 256, 0, stream>>>(params, w2t);
    decor_main<<<512, 256, 0, stream>>>(xin, w2t, out);
}

// Round 3
// 85.318 us; speedup vs baseline: 1.0618x; 1.0618x over previous
//
#include <hip/hip_runtime.h>
#include <hip/hip_bf16.h>

// out[n,v] = x[n,v] + sum_{c<v} x[n,c] * sum_k B_k(x[n,c]) * params[k, v(v-1)/2+c]
// GEMM form: G[n][c*16+k] = x[n,c]*B_k(x[n,c]);  W2T[v][c*16+k] = params or 0
// A-fragments built fully in registers (no LDS, no barriers); one shfl_xor(16)
// exchanges partner half-blocks. mfma_f32_16x16x32_f16, 24 MFMA / 16-sample tile.

#define PPAIR 496

typedef _Float16 f16x8 __attribute__((ext_vector_type(8)));
typedef float f32x4 __attribute__((ext_vector_type(4)));
typedef unsigned int u32;
typedef unsigned int u32x4 __attribute__((ext_vector_type(4)));

// ---- prep: build W2T [32][512] f16 from params [16][496] f32 ----
__global__ __launch_bounds__(256) void prep_w2t(const float* __restrict__ params,
                                                unsigned short* __restrict__ w2t) {
    int idx = blockIdx.x * 256 + threadIdx.x;   // 0 .. 32*512-1
    int v = idx >> 9;
    int c = (idx >> 4) & 31, k = idx & 15;
    float w = 0.0f;
    if (c < v) w = params[k * PPAIR + (v * (v - 1)) / 2 + c];
    _Float16 h = (_Float16)w;
    w2t[idx] = __builtin_bit_cast(unsigned short, h);
}

__global__ __launch_bounds__(256, 2) void decor_main(const float* __restrict__ xin,
                                                     const unsigned short* __restrict__ w2t,
                                                     float* __restrict__ out) {
    const int tid = threadIdx.x;
    const int wv = tid >> 6;
    const int l = tid & 63;
    const int s = l & 15;           // MFMA row/col lane id
    const int q = l >> 4;           // quarter-wave id (K-slot group)
    const int qp = q & 1;           // pairing parity (partner = lane ^ 16)
    const int sigma = ((q & 1) << 1) | (q >> 1);  // 0,2,1,3 : channel offset this lane computes

    // ---- B fragments in registers, t-pairing swapped at load (free):
    // b1[u][e] pairs with {keep,recv} A-frags; t = 2u + (qp ? 1-e : e)
    f16x8 b1[8][2];   // nt=1 (out cols 16..31), all u
    f16x8 b0[4][2];   // nt=0 (out cols 0..15), only u<4 (c<=15 because c<v<=15)
#pragma unroll
    for (int u = 0; u < 8; ++u) {
#pragma unroll
        for (int e = 0; e < 2; ++e) {
            int t = 2 * u + (qp ? (1 - e) : e);
            b1[u][e] = *(const f16x8*)(w2t + (16 + s) * 512 + t * 32 + q * 8);
            if (u < 4) b0[u][e] = *(const f16x8*)(w2t + s * 512 + t * 32 + q * 8);
        }
    }

    const float xmax = 5.999988f;          // hi - 1e-6*(hi-lo)
    const float sc = 13.0f / 12.0f;        // 1/h in u-space

    for (int tile = 0; tile < 4; ++tile) {
        const int S0 = blockIdx.x * 256 + wv * 64 + tile * 16;
        const float* xrow = xin + (S0 + s) * 32 + sigma;
        float xv[8];
#pragma unroll
        for (int u = 0; u < 8; ++u) xv[u] = xrow[4 * u];

        f32x4 acc0 = {0.f, 0.f, 0.f, 0.f};
        f32x4 acc1 = {0.f, 0.f, 0.f, 0.f};

#pragma unroll
        for (int u = 0; u < 8; ++u) {
            float x = xv[u];
            float xc = fminf(fmaxf(x, -6.0f), xmax);
            float uu = fmaf(xc, sc, 6.5f);          // (xc+6)*13/12
            int mi = (int)uu;
            mi = mi < 12 ? mi : 12;                 // span 0..12; nonzero basis m..m+3
            float mf = (float)mi;
            float r = uu - mf;                      // in [0,1)
            float N0, N1, N2, N3;
            if (__all(mi >= 3 && mi <= 9)) {
                // interior span: uniform cubic B-spline closed form
                float omr = 1.0f - r;
                float r2 = r * r, r3 = r2 * r;
                float o2 = omr * omr;
                N0 = o2 * omr * (1.0f / 6.0f);
                N3 = r3 * (1.0f / 6.0f);
                N1 = fmaf(0.5f, r3, (2.0f / 3.0f) - r2);
                N2 = 1.0f - N0 - N1 - N3;
            } else {
                // general clamped-knot recursion in u-space (integer knot gaps)
                float t13 = 13.0f - mf;
                float af = fminf(mf, 1.0f);
                float bf = fminf(mf, 2.0f);
                float cf = fminf(t13, 2.0f);
                float df = fminf(t13, 3.0f);
                float r1 = 1.0f - r;
                float l2 = r + af, rr2 = cf - r;
                float l3 = r + bf, rr3 = df - r;
                // deg 2
                float iv = (af == 0.0f) ? 1.0f : 0.5f;          // 1/(1+a)
                float T = r1 * iv;
                float M0 = r1 * T;
                float sv = l2 * T;
                float iv2 = (cf == 1.0f) ? 1.0f : 0.5f;         // 1/c2
                float T2 = r * iv2;
                float M1 = fmaf(rr2, T2, sv);
                float M2 = r * T2;
                // deg 3
                float iv3 = 0.5f;
                iv3 = (bf == 0.0f) ? 1.0f : iv3;                // 1/(1+b)
                iv3 = (bf == 2.0f) ? (1.0f / 3.0f) : iv3;
                T = M0 * iv3;
                N0 = r1 * T;
                sv = l3 * T;
                float g14 = af + cf;                            // a+c2 in {2,3}
                float iv4 = (g14 == 2.0f) ? 0.5f : (1.0f / 3.0f);
                T = M1 * iv4;
                N1 = fmaf(rr2, T, sv);
                sv = l2 * T;
                float iv5 = 0.5f;
                iv5 = (df == 1.0f) ? 1.0f : iv5;                // 1/d3
                iv5 = (df == 3.0f) ? (1.0f / 3.0f) : iv5;
                T = M2 * iv5;
                N2 = fmaf(rr3, T, sv);
                N3 = r * T;
            }
            // payload: g at f16 slots mi..mi+3 (dword pairs)
            float g0 = x * N0, g1 = x * N1, g2 = x * N2, g3 = x * N3;
            int e = mi & 1;
            float aa = e ? 0.0f : g0, bb = e ? g0 : g1;
            float cc = e ? g1 : g2, dd = e ? g2 : g3;
            float ee = e ? g3 : 0.0f;
            u32 p0 = __builtin_bit_cast(u32, __builtin_amdgcn_cvt_pkrtz(aa, bb));
            u32 p1 = __builtin_bit_cast(u32, __builtin_amdgcn_cvt_pkrtz(cc, dd));
            u32 p2 = __builtin_bit_cast(u32, __builtin_amdgcn_cvt_pkrtz(ee, 0.0f));
            int w0 = mi >> 1;
            int dlt = w0 & 1;
            // 4-dword container at even dword j0 = w0&6 (payload offset dlt)
            u32 C0 = dlt ? 0u : p0;
            u32 C1 = dlt ? p0 : p1;
            u32 C2 = dlt ? p1 : p2;
            u32 C3 = dlt ? p2 : 0u;
            // rotate-place; XOR 4*(qp) folds the keep/send half-swap in for free
            int j0 = (w0 & 6) ^ (qp << 2);
            bool b2 = (j0 & 2) != 0;
            u32 t0 = b2 ? 0u : C0;
            u32 t1 = b2 ? 0u : C1;
            u32 t2 = b2 ? C0 : C2;
            u32 t3 = b2 ? C1 : C3;
            u32 t4 = b2 ? C2 : 0u;
            u32 t5 = b2 ? C3 : 0u;     // t6 = t7 = 0
            bool b4 = (j0 & 4) != 0;
            u32 B0 = b4 ? t4 : t0;
            u32 B1 = b4 ? t5 : t1;
            u32 B2 = b4 ? 0u : t2;
            u32 B3 = b4 ? 0u : t3;
            u32 B4 = b4 ? t0 : t4;
            u32 B5 = b4 ? t1 : t5;
            u32 B6 = b4 ? t2 : 0u;
            u32 B7 = b4 ? t3 : 0u;
            // exchange send-half with partner lane (q ^ 1)
            u32 R0 = (u32)__shfl_xor((int)B4, 16);
            u32 R1 = (u32)__shfl_xor((int)B5, 16);
            u32 R2 = (u32)__shfl_xor((int)B6, 16);
            u32 R3 = (u32)__shfl_xor((int)B7, 16);
            u32x4 kp = {B0, B1, B2, B3};
            u32x4 rc = {R0, R1, R2, R3};
            f16x8 ka = __builtin_bit_cast(f16x8, kp);
            f16x8 ra = __builtin_bit_cast(f16x8, rc);
            acc1 = __builtin_amdgcn_mfma_f32_16x16x32_f16(ka, b1[u][0], acc1, 0, 0, 0);
            acc1 = __builtin_amdgcn_mfma_f32_16x16x32_f16(ra, b1[u][1], acc1, 0, 0, 0);
            if (u < 4) {
                acc0 = __builtin_amdgcn_mfma_f32_16x16x32_f16(ka, b0[u][0], acc0, 0, 0, 0);
                acc0 = __builtin_amdgcn_mfma_f32_16x16x32_f16(ra, b0[u][1], acc0, 0, 0, 0);
            }
        }

        // ---- epilogue: D[row=(q*4+r)][col=s(+16)] ; out = x + D
#pragma unroll
        for (int rI = 0; rI < 4; ++rI) {
            int sample = S0 + q * 4 + rI;
            int base = sample * 32;
            out[base + s]      = xin[base + s]      + acc0[rI];
            out[base + 16 + s] = xin[base + 16 + s] + acc1[rI];
        }
    }
}

extern "C" void kernel_launch(void* const* d_in, const int* in_sizes, int n_in,
                              void* d_out, int out_size, void* d_ws, size_t ws_size,
                              hipStream_t stream) {
    const float* xin = (const float*)d_in[0];
    const float* params = (const float*)d_in[1];
    float* out = (float*)d_out;
    unsigned short* w2t = (unsigned short*)d_ws;   // 32*512 f16 = 32 KB scratch

    prep_w2t<<<64, 256, 0, stream>>>(params, w2t);
    decor_main<<<512, 256, 0, stream>>>(xin, w2t, out);
}

// Round 5
// 84.618 us; speedup vs baseline: 1.0706x; 1.0083x over previous
//
#include <hip/hip_runtime.h>
#include <hip/hip_bf16.h>

// out[n,v] = x[n,v] + sum_{c<v} x[n,c] * sum_k B_k(x[n,c]) * params[k, v(v-1)/2+c]
// GEMM form: G[n][c*16+k] = x[n,c]*B_k(x[n,c]);  W2T[v][c*16+k] = params or 0
// A-fragments built fully in registers (no LDS, no barriers); one shfl_xor(16)
// exchanges partner half-blocks. mfma_f32_16x16x32_f16, 24 MFMA / 16-sample tile.
// R4 (resubmit after broker timeout): cross-tile x prefetch + epilogue-x prefetch
// + 3 waves/SIMD + med3 clamp.

#define PPAIR 496

typedef _Float16 f16x8 __attribute__((ext_vector_type(8)));
typedef float f32x4 __attribute__((ext_vector_type(4)));
typedef unsigned int u32;
typedef unsigned int u32x4 __attribute__((ext_vector_type(4)));

// ---- prep: build W2T [32][512] f16 from params [16][496] f32 ----
__global__ __launch_bounds__(256) void prep_w2t(const float* __restrict__ params,
                                                unsigned short* __restrict__ w2t) {
    int idx = blockIdx.x * 256 + threadIdx.x;   // 0 .. 32*512-1
    int v = idx >> 9;
    int c = (idx >> 4) & 31, k = idx & 15;
    float w = 0.0f;
    if (c < v) w = params[k * PPAIR + (v * (v - 1)) / 2 + c];
    _Float16 h = (_Float16)w;
    w2t[idx] = __builtin_bit_cast(unsigned short, h);
}

__global__ __launch_bounds__(256, 3) void decor_main(const float* __restrict__ xin,
                                                     const unsigned short* __restrict__ w2t,
                                                     float* __restrict__ out) {
    const int tid = threadIdx.x;
    const int wv = tid >> 6;
    const int l = tid & 63;
    const int s = l & 15;           // MFMA row/col lane id
    const int q = l >> 4;           // quarter-wave id (K-slot group)
    const int qp = q & 1;           // pairing parity (partner = lane ^ 16)
    const int sigma = ((q & 1) << 1) | (q >> 1);  // 0,2,1,3 : channel offset this lane computes

    // ---- B fragments in registers, t-pairing swapped at load (free):
    // b1[u][e] pairs with {keep,recv} A-frags; t = 2u + (qp ? 1-e : e)
    f16x8 b1[8][2];   // nt=1 (out cols 16..31), all u
    f16x8 b0[4][2];   // nt=0 (out cols 0..15), only u<4 (c<=15 because c<v<=15)
#pragma unroll
    for (int u = 0; u < 8; ++u) {
#pragma unroll
        for (int e = 0; e < 2; ++e) {
            int t = 2 * u + (qp ? (1 - e) : e);
            b1[u][e] = *(const f16x8*)(w2t + (16 + s) * 512 + t * 32 + q * 8);
            if (u < 4) b0[u][e] = *(const f16x8*)(w2t + s * 512 + t * 32 + q * 8);
        }
    }

    const float sc = 13.0f / 12.0f;        // 1/h in u-space
    const int S0w = blockIdx.x * 256 + wv * 64;

    // ---- prime the pipeline: tile 0 basis x-loads
    float xv[8];
    {
        const float* xr = xin + (S0w + s) * 32 + sigma;
#pragma unroll
        for (int u = 0; u < 8; ++u) xv[u] = xr[4 * u];
    }

#pragma unroll
    for (int tile = 0; tile < 4; ++tile) {
        const int T0 = S0w + tile * 16;

        // epilogue x for CURRENT tile (L1-resident after basis loads) — issue early
        float xe0[4], xe1[4];
#pragma unroll
        for (int rI = 0; rI < 4; ++rI) {
            int base = (T0 + q * 4 + rI) * 32;
            xe0[rI] = xin[base + s];
            xe1[rI] = xin[base + 16 + s];
        }
        // basis x for NEXT tile — issue before compute so HBM latency hides
        float xvn[8];
        if (tile < 3) {
            const float* xr = xin + (T0 + 16 + s) * 32 + sigma;
#pragma unroll
            for (int u = 0; u < 8; ++u) xvn[u] = xr[4 * u];
        }

        f32x4 acc0 = {0.f, 0.f, 0.f, 0.f};
        f32x4 acc1 = {0.f, 0.f, 0.f, 0.f};

#pragma unroll
        for (int u = 0; u < 8; ++u) {
            float x = xv[u];
            float uu = fmaf(x, sc, 6.5f);           // (x+6)*13/12, then clamp in u-space
            uu = fminf(fmaxf(uu, 0.0f), 12.999987f); // == clip(x, -6, 5.999988) mapped (v_med3)
            int mi = (int)uu;                        // span 0..12; nonzero basis m..m+3
            float mf = (float)mi;
            float r = uu - mf;                       // in [0,1)
            float N0, N1, N2, N3;
            if (__all(mi >= 3 && mi <= 9)) {
                // interior span: uniform cubic B-spline closed form
                float omr = 1.0f - r;
                float r2 = r * r, r3 = r2 * r;
                float o2 = omr * omr;
                N0 = o2 * omr * (1.0f / 6.0f);
                N3 = r3 * (1.0f / 6.0f);
                N1 = fmaf(0.5f, r3, (2.0f / 3.0f) - r2);
                N2 = 1.0f - N0 - N1 - N3;
            } else {
                // general clamped-knot recursion in u-space (integer knot gaps)
                float t13 = 13.0f - mf;
                float af = fminf(mf, 1.0f);
                float bf = fminf(mf, 2.0f);
                float cf = fminf(t13, 2.0f);
                float df = fminf(t13, 3.0f);
                float r1 = 1.0f - r;
                float l2 = r + af, rr2 = cf - r;
                float l3 = r + bf, rr3 = df - r;
                // deg 2
                float iv = (af == 0.0f) ? 1.0f : 0.5f;          // 1/(1+a)
                float T = r1 * iv;
                float M0 = r1 * T;
                float sv = l2 * T;
                float iv2 = (cf == 1.0f) ? 1.0f : 0.5f;         // 1/c2
                float T2 = r * iv2;
                float M1 = fmaf(rr2, T2, sv);
                float M2 = r * T2;
                // deg 3
                float iv3 = 0.5f;
                iv3 = (bf == 0.0f) ? 1.0f : iv3;                // 1/(1+b)
                iv3 = (bf == 2.0f) ? (1.0f / 3.0f) : iv3;
                T = M0 * iv3;
                N0 = r1 * T;
                sv = l3 * T;
                float g14 = af + cf;                            // a+c2 in {2,3}
                float iv4 = (g14 == 2.0f) ? 0.5f : (1.0f / 3.0f);
                T = M1 * iv4;
                N1 = fmaf(rr2, T, sv);
                sv = l2 * T;
                float iv5 = 0.5f;
                iv5 = (df == 1.0f) ? 1.0f : iv5;                // 1/d3
                iv5 = (df == 3.0f) ? (1.0f / 3.0f) : iv5;
                T = M2 * iv5;
                N2 = fmaf(rr3, T, sv);
                N3 = r * T;
            }
            // payload: g at f16 slots mi..mi+3 (dword pairs)
            float g0 = x * N0, g1 = x * N1, g2 = x * N2, g3 = x * N3;
            int e = mi & 1;
            float aa = e ? 0.0f : g0, bb = e ? g0 : g1;
            float cc = e ? g1 : g2, dd = e ? g2 : g3;
            float ee = e ? g3 : 0.0f;
            u32 p0 = __builtin_bit_cast(u32, __builtin_amdgcn_cvt_pkrtz(aa, bb));
            u32 p1 = __builtin_bit_cast(u32, __builtin_amdgcn_cvt_pkrtz(cc, dd));
            u32 p2 = __builtin_bit_cast(u32, __builtin_amdgcn_cvt_pkrtz(ee, 0.0f));
            int w0 = mi >> 1;
            int dlt = w0 & 1;
            // 4-dword container at even dword j0 = w0&6 (payload offset dlt)
            u32 C0 = dlt ? 0u : p0;
            u32 C1 = dlt ? p0 : p1;
            u32 C2 = dlt ? p1 : p2;
            u32 C3 = dlt ? p2 : 0u;
            // rotate-place; XOR 4*(qp) folds the keep/send half-swap in for free
            int j0 = (w0 & 6) ^ (qp << 2);
            bool b2 = (j0 & 2) != 0;
            u32 t0 = b2 ? 0u : C0;
            u32 t1 = b2 ? 0u : C1;
            u32 t2 = b2 ? C0 : C2;
            u32 t3 = b2 ? C1 : C3;
            u32 t4 = b2 ? C2 : 0u;
            u32 t5 = b2 ? C3 : 0u;     // t6 = t7 = 0
            bool b4 = (j0 & 4) != 0;
            u32 B0 = b4 ? t4 : t0;
            u32 B1 = b4 ? t5 : t1;
            u32 B2 = b4 ? 0u : t2;
            u32 B3 = b4 ? 0u : t3;
            u32 B4 = b4 ? t0 : t4;
            u32 B5 = b4 ? t1 : t5;
            u32 B6 = b4 ? t2 : 0u;
            u32 B7 = b4 ? t3 : 0u;
            // exchange send-half with partner lane (q ^ 1)
            u32 R0 = (u32)__shfl_xor((int)B4, 16);
            u32 R1 = (u32)__shfl_xor((int)B5, 16);
            u32 R2 = (u32)__shfl_xor((int)B6, 16);
            u32 R3 = (u32)__shfl_xor((int)B7, 16);
            u32x4 kp = {B0, B1, B2, B3};
            u32x4 rc = {R0, R1, R2, R3};
            f16x8 ka = __builtin_bit_cast(f16x8, kp);
            f16x8 ra = __builtin_bit_cast(f16x8, rc);
            acc1 = __builtin_amdgcn_mfma_f32_16x16x32_f16(ka, b1[u][0], acc1, 0, 0, 0);
            acc1 = __builtin_amdgcn_mfma_f32_16x16x32_f16(ra, b1[u][1], acc1, 0, 0, 0);
            if (u < 4) {
                acc0 = __builtin_amdgcn_mfma_f32_16x16x32_f16(ka, b0[u][0], acc0, 0, 0, 0);
                acc0 = __builtin_amdgcn_mfma_f32_16x16x32_f16(ra, b0[u][1], acc0, 0, 0, 0);
            }
        }

        // ---- epilogue: D[row=(q*4+r)][col=s(+16)] ; out = x + D
#pragma unroll
        for (int rI = 0; rI < 4; ++rI) {
            int sample = T0 + q * 4 + rI;
            int base = sample * 32;
            out[base + s]      = xe0[rI] + acc0[rI];
            out[base + 16 + s] = xe1[rI] + acc1[rI];
        }

        if (tile < 3) {
#pragma unroll
            for (int u = 0; u < 8; ++u) xv[u] = xvn[u];
        }
    }
}

extern "C" void kernel_launch(void* const* d_in, const int* in_sizes, int n_in,
                              void* d_out, int out_size, void* d_ws, size_t ws_size,
                              hipStream_t stream) {
    const float* xin = (const float*)d_in[0];
    const float* params = (const float*)d_in[1];
    float* out = (float*)d_out;
    unsigned short* w2t = (unsigned short*)d_ws;   // 32*512 f16 = 32 KB scratch

    prep_w2t<<<64, 256, 0, stream>>>(params, w2t);
    decor_main<<<512, 256, 0, stream>>>(xin, w2t, out);
}